// Round 7
// baseline (793.198 us; speedup 1.0000x reference)
//
#include <hip/hip_runtime.h>

// Shapes: B=2, L=2048, D_MODEL=1024, H=16, D_K=64
// Pipeline:
//  0) pack_mask: mask int32 [B][L][L] -> bit-packed u32 [B][L][L/32].
//  1) gemm_proj<0/1>: Q/K = x @ W^T (f32 in, f16 out, head-major [bh][l][64]).
//     Q pre-scaled by 1/16 = (1/sqrt(64)) * (1/2)  [entmax z = scores/2].
//  2) gemm_proj<2>: V projection, epilogue writes Vt [bh][64][l] directly.
//  3) attn_entmax: block = 32 queries x 2048 keys, 8 waves, XCD-swizzled grid.
//     Swapped QK^T (2 q-tiles share every K fragment) -> f16x2 scores in regs.
//     Entmax: 3 cross-wave Newton iters from tau0=zmax-1 (monotone from below),
//     filter survivors z > tau3-1e-3 into per-query f16 buckets (CAP=512),
//     quarter-wave bucket solve (4 Newton + 3 exact support refines),
//     P + PV direct from regs (Vt fragments shared by both q-tiles).
//  4) gemm_proj<3>: out = AO @ Wo^T -> f32 d_out.

typedef _Float16 f16;
typedef __attribute__((ext_vector_type(8))) _Float16 f16x8;
typedef __attribute__((ext_vector_type(4))) _Float16 f16x4;
typedef __attribute__((ext_vector_type(2))) _Float16 f16x2;
typedef __attribute__((ext_vector_type(4))) float f32x4;
typedef unsigned int u32;

static __device__ __forceinline__ f16x2 max2(f16x2 a, f16x2 b) {
    f16x2 r;
    r.x = a.x > b.x ? a.x : b.x;
    r.y = a.y > b.y ? a.y : b.y;
    return r;
}

// ---------------------------------------------------------------------------
// mask [2][2048][2048] int -> bits [2][2048][64] u32
// ---------------------------------------------------------------------------
__global__ __launch_bounds__(256)
void pack_mask(const int* __restrict__ mask, u32* __restrict__ bits)
{
    int idx = blockIdx.x * 256 + threadIdx.x;        // 0..262143
    const int4* p = (const int4*)&mask[(size_t)idx * 32];
    u32 v = 0;
#pragma unroll
    for (int i = 0; i < 8; i++) {
        int4 m = p[i];
        if (m.x != 0) v |= 1u << (i * 4 + 0);
        if (m.y != 0) v |= 1u << (i * 4 + 1);
        if (m.z != 0) v |= 1u << (i * 4 + 2);
        if (m.w != 0) v |= 1u << (i * 4 + 3);
    }
    bits[idx] = v;
}

// ---------------------------------------------------------------------------
// GEMM: C[M=4096, N=1024] = A[M,1024] * W[N,K=1024]^T
// MODE 0: Q (f16, *1/16, head-major)  1: K  2: V->Vt [bh][64][l]  3: OUT f32
// ---------------------------------------------------------------------------
template <int MODE>
__global__ __launch_bounds__(512)
void gemm_proj(const void* __restrict__ Ap, const float* __restrict__ Wp,
               void* __restrict__ Cp)
{
    __shared__ __align__(16) f16 As[128 * 40];
    __shared__ __align__(16) f16 Bs[128 * 40];

    const int tid = threadIdx.x;
    const int mBase = blockIdx.x * 128;
    const int nBase = blockIdx.y * 128;

    const int lane = tid & 63, w = tid >> 6;
    const int g = lane >> 4, c = lane & 15;
    const int wm = w >> 1, wn = w & 1;

    const int sr = tid >> 2;
    const int sq = tid & 3;

    f32x4 acc[2][4];
    const f32x4 vzero = {0.f, 0.f, 0.f, 0.f};
#pragma unroll
    for (int i = 0; i < 2; i++)
#pragma unroll
        for (int j = 0; j < 4; j++) acc[i][j] = vzero;

    for (int k0 = 0; k0 < 1024; k0 += 32) {
        __syncthreads();
        {
            f16x8 av;
            if constexpr (MODE == 3) {
                const f16* A = (const f16*)Ap;
                av = *(const f16x8*)&A[(size_t)(mBase + sr) * 1024 + k0 + sq * 8];
            } else {
                const float* A = (const float*)Ap;
                const float4* p = (const float4*)&A[(size_t)(mBase + sr) * 1024 + k0 + sq * 8];
                float4 x0 = p[0], x1 = p[1];
                av[0] = (f16)x0.x; av[1] = (f16)x0.y; av[2] = (f16)x0.z; av[3] = (f16)x0.w;
                av[4] = (f16)x1.x; av[5] = (f16)x1.y; av[6] = (f16)x1.z; av[7] = (f16)x1.w;
            }
            *(f16x8*)&As[sr * 40 + sq * 8] = av;

            const float4* pw = (const float4*)&Wp[(size_t)(nBase + sr) * 1024 + k0 + sq * 8];
            float4 w0 = pw[0], w1 = pw[1];
            f16x8 bv;
            bv[0] = (f16)w0.x; bv[1] = (f16)w0.y; bv[2] = (f16)w0.z; bv[3] = (f16)w0.w;
            bv[4] = (f16)w1.x; bv[5] = (f16)w1.y; bv[6] = (f16)w1.z; bv[7] = (f16)w1.w;
            *(f16x8*)&Bs[sr * 40 + sq * 8] = bv;
        }
        __syncthreads();

        f16x8 af[2], bf[4];
#pragma unroll
        for (int mt = 0; mt < 2; mt++)
            af[mt] = *(const f16x8*)&As[(wm * 32 + mt * 16 + c) * 40 + g * 8];
#pragma unroll
        for (int nt = 0; nt < 4; nt++)
            bf[nt] = *(const f16x8*)&Bs[(wn * 64 + nt * 16 + c) * 40 + g * 8];
#pragma unroll
        for (int mt = 0; mt < 2; mt++)
#pragma unroll
            for (int nt = 0; nt < 4; nt++)
                acc[mt][nt] = __builtin_amdgcn_mfma_f32_16x16x32_f16(af[mt], bf[nt], acc[mt][nt], 0, 0, 0);
    }

#pragma unroll
    for (int mt = 0; mt < 2; mt++)
#pragma unroll
        for (int nt = 0; nt < 4; nt++) {
            int row0 = mBase + wm * 32 + mt * 16 + g * 4;
            int col = nBase + wn * 64 + nt * 16 + c;
            if constexpr (MODE == 3) {
#pragma unroll
                for (int r = 0; r < 4; r++)
                    ((float*)Cp)[(size_t)(row0 + r) * 1024 + col] = acc[mt][nt][r];
            } else if constexpr (MODE == 2) {
                int b = row0 >> 11, l0 = row0 & 2047;
                int h = col >> 6, dk = col & 63;
                f16x4 pv;
#pragma unroll
                for (int r = 0; r < 4; r++) pv[r] = (f16)acc[mt][nt][r];
                *(f16x4*)&((f16*)Cp)[((size_t)(b * 16 + h) * 64 + dk) * 2048 + l0] = pv;
            } else {
#pragma unroll
                for (int r = 0; r < 4; r++) {
                    int row = row0 + r;
                    float v = acc[mt][nt][r];
                    if constexpr (MODE == 0) v *= 0.0625f;
                    int b = row >> 11, l = row & 2047;
                    int h = col >> 6, dk = col & 63;
                    ((f16*)Cp)[((size_t)(b * 16 + h) * 2048 + l) * 64 + dk] = (f16)v;
                }
            }
        }
}

// ---------------------------------------------------------------------------
// Attention + exact 1.5-entmax; 32 queries/block.
// ---------------------------------------------------------------------------
__global__ __launch_bounds__(512, 4)
void attn_entmax(const f16* __restrict__ Q, const f16* __restrict__ Kh,
                 const f16* __restrict__ Vt, const u32* __restrict__ mbits,
                 f16* __restrict__ AO)
{
    constexpr int CAP = 512;
    // Overlay: bucket f16[32][512] (32 KB) dies at the taus barrier;
    // Ored f32 [8][32][68] (69.6 KB) lives after it.
    __shared__ __align__(16) char LB[8 * 32 * 68 * 4];
    __shared__ int cntS[32];
    __shared__ float redM[8][32];
    __shared__ float redN[2][8][32][2];
    __shared__ float tau3s[32], zmaxs[32], taus[32];

    f16 (*bucket)[CAP] = (f16 (*)[CAP])LB;
    float* Ored = (float*)LB;

    const int tid = threadIdx.x;
    const int w = tid >> 6, lane = tid & 63;
    const int g = lane >> 4, c = lane & 15;

    // XCD-aware swizzle: 2048 blocks = 8 XCD x (4 bh x 64 q-blocks)
    const int bid = blockIdx.x;
    const int q7 = bid >> 3;
    const int bh = (bid & 7) * 4 + (q7 >> 6);
    const int qb = (q7 & 63) * 32;
    const int b = bh >> 4, h = bh & 15;
    const int kbase = w * 256;

    if (tid < 32) cntS[tid] = 0;

    // ---- Q B-fragments for the two q-tiles ----
    const f16* qpA = &Q[(size_t)(bh * 2048 + qb + c) * 64 + g * 8];
    const f16* qpB = qpA + 16 * 64;
    f16x8 bqA0 = *(const f16x8*)qpA;
    f16x8 bqA1 = *(const f16x8*)(qpA + 32);
    f16x8 bqB0 = *(const f16x8*)qpB;
    f16x8 bqB1 = *(const f16x8*)(qpB + 32);

    const uint4* mpA = (const uint4*)&mbits[(size_t)(b * 2048 + qb + c) * 64 + w * 8];
    const uint4* mpB = (const uint4*)&mbits[(size_t)(b * 2048 + qb + 16 + c) * 64 + w * 8];
    uint4 mA0 = mpA[0], mA1 = mpA[1], mB0 = mpB[0], mB1 = mpB[1];
    u32 mbA[8] = {mA0.x, mA0.y, mA0.z, mA0.w, mA1.x, mA1.y, mA1.z, mA1.w};
    u32 mbB[8] = {mB0.x, mB0.y, mB0.z, mB0.w, mB1.x, mB1.y, mB1.z, mB1.w};

    // ---- scores (swapped): lane holds keys {kbase+t*16+g*4+r} for queries qb+c, qb+16+c ----
    f16x2 hSA[32], hSB[32];
    const f32x4 vz = {0.f, 0.f, 0.f, 0.f};
    const f16* kp0 = &Kh[(size_t)(bh * 2048 + kbase + c) * 64 + g * 8];

    f16x8 ka0 = *(const f16x8*)kp0;
    f16x8 ka1 = *(const f16x8*)(kp0 + 32);
#pragma unroll
    for (int t = 0; t < 16; t++) {
        f16x8 kn0, kn1;
        if (t < 15) {
            const f16* kp = kp0 + (t + 1) * 16 * 64;
            kn0 = *(const f16x8*)kp;
            kn1 = *(const f16x8*)(kp + 32);
        }
        f32x4 zA = __builtin_amdgcn_mfma_f32_16x16x32_f16(ka0, bqA0, vz, 0, 0, 0);
        zA = __builtin_amdgcn_mfma_f32_16x16x32_f16(ka1, bqA1, zA, 0, 0, 0);
        f32x4 zB = __builtin_amdgcn_mfma_f32_16x16x32_f16(ka0, bqB0, vz, 0, 0, 0);
        zB = __builtin_amdgcn_mfma_f32_16x16x32_f16(ka1, bqB1, zB, 0, 0, 0);
        u32 b4A = mbA[t >> 1] >> ((t & 1) * 16 + g * 4);
        u32 b4B = mbB[t >> 1] >> ((t & 1) * 16 + g * 4);
#pragma unroll
        for (int r = 0; r < 4; r++) {
            if (!((b4A >> r) & 1)) zA[r] = -30000.f;
            if (!((b4B >> r) & 1)) zB[r] = -30000.f;
        }
        f16x2 a0, a1, b0, b1;
        a0.x = (f16)zA[0]; a0.y = (f16)zA[1];
        a1.x = (f16)zA[2]; a1.y = (f16)zA[3];
        b0.x = (f16)zB[0]; b0.y = (f16)zB[1];
        b1.x = (f16)zB[2]; b1.y = (f16)zB[3];
        hSA[2 * t] = a0; hSA[2 * t + 1] = a1;
        hSB[2 * t] = b0; hSB[2 * t + 1] = b1;
        ka0 = kn0; ka1 = kn1;
    }

    // ---- zmax per query ----
    f16x2 mA = hSA[0], mB = hSB[0];
#pragma unroll
    for (int i = 1; i < 32; i++) { mA = max2(mA, hSA[i]); mB = max2(mB, hSB[i]); }
    float zxA = fmaxf((float)mA.x, (float)mA.y);
    float zxB = fmaxf((float)mB.x, (float)mB.y);
    zxA = fmaxf(zxA, __shfl_xor(zxA, 16)); zxA = fmaxf(zxA, __shfl_xor(zxA, 32));
    zxB = fmaxf(zxB, __shfl_xor(zxB, 16)); zxB = fmaxf(zxB, __shfl_xor(zxB, 32));
    if (lane < 16) { redM[w][c] = zxA; redM[w][16 + c] = zxB; }
    __syncthreads();
    float zmaxA = -3e38f, zmaxB = -3e38f;
#pragma unroll
    for (int ww = 0; ww < 8; ww++) {
        zmaxA = fmaxf(zmaxA, redM[ww][c]);
        zmaxB = fmaxf(zmaxB, redM[ww][16 + c]);
    }

    // ---- 3 cross-wave Newton iters from below -> tau3 <= tau* ----
    float tauA = zmaxA - 1.0f, tauB = zmaxB - 1.0f;
    int buf = 0;
#pragma unroll 1
    for (int it = 0; it < 3; ++it) {
        float s1A = 0.f, s2A = 0.f, s1B = 0.f, s2B = 0.f;
#pragma unroll
        for (int i = 0; i < 32; i++) {
            float la = fmaxf((float)hSA[i].x - tauA, 0.f);
            float ha = fmaxf((float)hSA[i].y - tauA, 0.f);
            s1A += la + ha; s2A = fmaf(la, la, fmaf(ha, ha, s2A));
            float lb = fmaxf((float)hSB[i].x - tauB, 0.f);
            float hb = fmaxf((float)hSB[i].y - tauB, 0.f);
            s1B += lb + hb; s2B = fmaf(lb, lb, fmaf(hb, hb, s2B));
        }
        s1A += __shfl_xor(s1A, 16); s1A += __shfl_xor(s1A, 32);
        s2A += __shfl_xor(s2A, 16); s2A += __shfl_xor(s2A, 32);
        s1B += __shfl_xor(s1B, 16); s1B += __shfl_xor(s1B, 32);
        s2B += __shfl_xor(s2B, 16); s2B += __shfl_xor(s2B, 32);
        if (lane < 16) {
            redN[buf][w][c][0] = s1A; redN[buf][w][c][1] = s2A;
            redN[buf][w][16 + c][0] = s1B; redN[buf][w][16 + c][1] = s2B;
        }
        __syncthreads();
        float aA = 0.f, fA = 0.f, aB = 0.f, fB = 0.f;
#pragma unroll
        for (int ww = 0; ww < 8; ww++) {
            float2 vA = *(const float2*)&redN[buf][ww][c][0];
            float2 vB = *(const float2*)&redN[buf][ww][16 + c][0];
            aA += vA.x; fA += vA.y; aB += vB.x; fB += vB.y;
        }
        if (aA > 1e-12f) tauA = fminf(tauA + (fA - 1.0f) / (2.0f * aA), zmaxA - 1e-3f);
        if (aB > 1e-12f) tauB = fminf(tauB + (fB - 1.0f) / (2.0f * aB), zmaxB - 1e-3f);
        buf ^= 1;
    }
    if (w == 0 && lane < 16) {
        tau3s[c] = tauA; tau3s[16 + c] = tauB;
        zmaxs[c] = zmaxA; zmaxs[16 + c] = zmaxB;
    }

    // ---- filter survivors into per-query f16 buckets ----
    const float thrA = tauA - 1e-3f, thrB = tauB - 1e-3f;
#pragma unroll
    for (int i = 0; i < 32; i++) {
        float la = (float)hSA[i].x, ha = (float)hSA[i].y;
        if (la > thrA) { int id = atomicAdd(&cntS[c], 1); if (id < CAP) bucket[c][id] = hSA[i].x; }
        if (ha > thrA) { int id = atomicAdd(&cntS[c], 1); if (id < CAP) bucket[c][id] = hSA[i].y; }
        float lb = (float)hSB[i].x, hb = (float)hSB[i].y;
        if (lb > thrB) { int id = atomicAdd(&cntS[16 + c], 1); if (id < CAP) bucket[16 + c][id] = hSB[i].x; }
        if (hb > thrB) { int id = atomicAdd(&cntS[16 + c], 1); if (id < CAP) bucket[16 + c][id] = hSB[i].y; }
    }
    __syncthreads();

    // ---- bucket solve: quarter-wave per query (4 queries / wave) ----
    {
        const int qi = 4 * w + (lane >> 4);
        const int sl = lane & 15;
        const int cnt = min(cntS[qi], CAP);
        const int ns = (cnt + 15) >> 4;
        float tq = tau3s[qi];
        const float zq = zmaxs[qi];
#pragma unroll 1
        for (int it = 0; it < 4; ++it) {
            float s1 = 0.f, s2 = 0.f;
#pragma unroll 1
            for (int s = 0; s < ns; s++) {
                int i = sl + 16 * s;
                float v = (i < cnt) ? (float)bucket[qi][i] : -1e30f;
                float d = fmaxf(v - tq, 0.f);
                s1 += d; s2 = fmaf(d, d, s2);
            }
#pragma unroll
            for (int off = 1; off <= 8; off <<= 1) {
                s1 += __shfl_xor(s1, off);
                s2 += __shfl_xor(s2, off);
            }
            if (s1 > 1e-12f) tq = fminf(tq + (s2 - 1.0f) / (2.0f * s1), zq - 1e-3f);
        }
#pragma unroll 1
        for (int rf = 0; rf < 3; ++rf) {
            float kc = 0.f, s1 = 0.f, s2 = 0.f;
#pragma unroll 1
            for (int s = 0; s < ns; s++) {
                int i = sl + 16 * s;
                float v = (i < cnt) ? (float)bucket[qi][i] : -1e30f;
                float d = v - tq;
                if (d > 0.f) { kc += 1.f; s1 += d; s2 = fmaf(d, d, s2); }
            }
#pragma unroll
            for (int off = 1; off <= 8; off <<= 1) {
                kc += __shfl_xor(kc, off);
                s1 += __shfl_xor(s1, off);
                s2 += __shfl_xor(s2, off);
            }
            float K_ = fmaxf(kc, 1.0f);
            float disc = fmaxf(s1 * s1 - K_ * (s2 - 1.0f), 0.f);
            tq += (s1 - sqrtf(disc)) / K_;
        }
        if (sl == 0) taus[qi] = tq;
    }
    __syncthreads();     // taus ready; bucket dead -> LB becomes Ored

    // ---- P = ((z-tau)_+)^2 -> PV from regs; Vt frags shared by both q-tiles ----
    const float tcA = taus[c], tcB = taus[16 + c];
    f32x4 O0[4], O1[4];
#pragma unroll
    for (int nd = 0; nd < 4; nd++) { O0[nd] = vz; O1[nd] = vz; }
#pragma unroll
    for (int t = 0; t < 16; t++) {
        f16x4 pfA, pfB;
        {
            float d0 = fmaxf((float)hSA[2 * t].x - tcA, 0.f);
            float d1 = fmaxf((float)hSA[2 * t].y - tcA, 0.f);
            float d2 = fmaxf((float)hSA[2 * t + 1].x - tcA, 0.f);
            float d3 = fmaxf((float)hSA[2 * t + 1].y - tcA, 0.f);
            pfA[0] = (f16)(d0 * d0); pfA[1] = (f16)(d1 * d1);
            pfA[2] = (f16)(d2 * d2); pfA[3] = (f16)(d3 * d3);
            float e0 = fmaxf((float)hSB[2 * t].x - tcB, 0.f);
            float e1 = fmaxf((float)hSB[2 * t].y - tcB, 0.f);
            float e2 = fmaxf((float)hSB[2 * t + 1].x - tcB, 0.f);
            float e3 = fmaxf((float)hSB[2 * t + 1].y - tcB, 0.f);
            pfB[0] = (f16)(e0 * e0); pfB[1] = (f16)(e1 * e1);
            pfB[2] = (f16)(e2 * e2); pfB[3] = (f16)(e3 * e3);
        }
        const int j0 = kbase + t * 16;
#pragma unroll
        for (int nd = 0; nd < 4; nd++) {
            f16x4 va = *(const f16x4*)&Vt[(size_t)(bh * 64 + nd * 16 + c) * 2048 + j0 + g * 4];
            O0[nd] = __builtin_amdgcn_mfma_f32_16x16x16f16(va, pfA, O0[nd], 0, 0, 0);
            O1[nd] = __builtin_amdgcn_mfma_f32_16x16x16f16(va, pfB, O1[nd], 0, 0, 0);
        }
    }

    // ---- cross-wave O reduction (Ored overlays bucket; taus barrier separates) ----
#pragma unroll
    for (int nd = 0; nd < 4; nd++) {
        *(f32x4*)&Ored[(w * 32 + c) * 68 + nd * 16 + g * 4] = O0[nd];
        *(f32x4*)&Ored[(w * 32 + 16 + c) * 68 + nd * 16 + g * 4] = O1[nd];
    }
    __syncthreads();

    const int qr = tid >> 4;          // 0..31
    const int d0 = (tid & 15) * 4;    // 0..60
    float4 acc = {0.f, 0.f, 0.f, 0.f};
#pragma unroll
    for (int ww = 0; ww < 8; ww++) {
        float4 v = *(const float4*)&Ored[(ww * 32 + qr) * 68 + d0];
        acc.x += v.x; acc.y += v.y; acc.z += v.z; acc.w += v.w;
    }
    f16x4 pk;
    pk[0] = (f16)acc.x; pk[1] = (f16)acc.y; pk[2] = (f16)acc.z; pk[3] = (f16)acc.w;
    *(f16x4*)&AO[(size_t)(b * 2048 + qb + qr) * 1024 + h * 64 + d0] = pk;
}

// ---------------------------------------------------------------------------
extern "C" void kernel_launch(void* const* d_in, const int* in_sizes, int n_in,
                              void* d_out, int out_size, void* d_ws, size_t ws_size,
                              hipStream_t stream)
{
    const float* q  = (const float*)d_in[0];
    const float* k  = (const float*)d_in[1];
    const float* v  = (const float*)d_in[2];
    const int* mask = (const int*)d_in[3];
    const float* wq = (const float*)d_in[4];
    const float* wk = (const float*)d_in[5];
    const float* wv = (const float*)d_in[6];
    const float* wo = (const float*)d_in[7];

    char* ws = (char*)d_ws;
    const size_t SZ = 8388608ull;            // 8 MB per f16 buffer
    f16* Qb  = (f16*)(ws);
    f16* Kb  = (f16*)(ws + SZ);
    f16* Vtb = (f16*)(ws + 2 * SZ);
    f16* AOb = (f16*)(ws + 3 * SZ);
    u32* Mb  = (u32*)(ws + 4 * SZ);          // 1 MB packed mask

    pack_mask<<<1024, 256, 0, stream>>>(mask, Mb);

    dim3 gg(32, 8);
    gemm_proj<0><<<gg, 512, 0, stream>>>(q, wq, Qb);
    gemm_proj<1><<<gg, 512, 0, stream>>>(k, wk, Kb);
    gemm_proj<2><<<gg, 512, 0, stream>>>(v, wv, Vtb);
    attn_entmax<<<2048, 512, 0, stream>>>(Qb, Kb, Vtb, Mb, AOb);
    gemm_proj<3><<<gg, 512, 0, stream>>>(AOb, wo, d_out);
}

// Round 8
// 674.032 us; speedup vs baseline: 1.1768x; 1.1768x over previous
//
#include <hip/hip_runtime.h>

// Shapes: B=2, L=2048, D_MODEL=1024, H=16, D_K=64
// Pipeline:
//  0) pack_mask: mask int32 [B][L][L] -> bit-packed u32 [B][L][L/32].
//  1) gemm_proj<0/1>: Q/K = x @ W^T (f32 in, f16 out, head-major [bh][l][64]).
//     Q pre-scaled by 1/16 = (1/sqrt(64)) * (1/2)  [entmax z = scores/2].
//  2) gemm_proj<2>: V projection, epilogue writes Vt [bh][64][l] directly.
//  3) attn_entmax: block = 16 queries x 2048 keys, 8 waves, XCD-swizzled grid.
//     Swapped QK^T with explicit 2-tile double-buffered K prefetch -> f16x2 scores
//     in regs. Entmax: 2 cross-wave Newton iters (PACKED f16 scans) from
//     tau0=zmax-1 (monotone from below, 0.01 margin), filter survivors into
//     per-query f16 buckets (CAP=512), quarter-wave bucket solve (4 Newton +
//     3 exact support refines, f32). P in packed f16; PV with double-buffered
//     V prefetch (chunk 0 issued before the solve phase).
//  4) gemm_proj<3>: out = AO @ Wo^T -> f32 d_out.

typedef _Float16 f16;
typedef __attribute__((ext_vector_type(8))) _Float16 f16x8;
typedef __attribute__((ext_vector_type(4))) _Float16 f16x4;
typedef __attribute__((ext_vector_type(2))) _Float16 f16x2;
typedef __attribute__((ext_vector_type(4))) float f32x4;
typedef unsigned int u32;

static __device__ __forceinline__ f16x2 max2(f16x2 a, f16x2 b) {
    f16x2 r;
    r.x = a.x > b.x ? a.x : b.x;
    r.y = a.y > b.y ? a.y : b.y;
    return r;
}

// ---------------------------------------------------------------------------
// mask [2][2048][2048] int -> bits [2][2048][64] u32
// ---------------------------------------------------------------------------
__global__ __launch_bounds__(256)
void pack_mask(const int* __restrict__ mask, u32* __restrict__ bits)
{
    int idx = blockIdx.x * 256 + threadIdx.x;        // 0..262143
    const int4* p = (const int4*)&mask[(size_t)idx * 32];
    u32 v = 0;
#pragma unroll
    for (int i = 0; i < 8; i++) {
        int4 m = p[i];
        if (m.x != 0) v |= 1u << (i * 4 + 0);
        if (m.y != 0) v |= 1u << (i * 4 + 1);
        if (m.z != 0) v |= 1u << (i * 4 + 2);
        if (m.w != 0) v |= 1u << (i * 4 + 3);
    }
    bits[idx] = v;
}

// ---------------------------------------------------------------------------
// GEMM: C[M=4096, N=1024] = A[M,1024] * W[N,K=1024]^T
// MODE 0: Q (f16, *1/16, head-major)  1: K  2: V->Vt [bh][64][l]  3: OUT f32
// ---------------------------------------------------------------------------
template <int MODE>
__global__ __launch_bounds__(512)
void gemm_proj(const void* __restrict__ Ap, const float* __restrict__ Wp,
               void* __restrict__ Cp)
{
    __shared__ __align__(16) f16 As[128 * 40];
    __shared__ __align__(16) f16 Bs[128 * 40];

    const int tid = threadIdx.x;
    const int mBase = blockIdx.x * 128;
    const int nBase = blockIdx.y * 128;

    const int lane = tid & 63, w = tid >> 6;
    const int g = lane >> 4, c = lane & 15;
    const int wm = w >> 1, wn = w & 1;

    const int sr = tid >> 2;
    const int sq = tid & 3;

    f32x4 acc[2][4];
    const f32x4 vzero = {0.f, 0.f, 0.f, 0.f};
#pragma unroll
    for (int i = 0; i < 2; i++)
#pragma unroll
        for (int j = 0; j < 4; j++) acc[i][j] = vzero;

    for (int k0 = 0; k0 < 1024; k0 += 32) {
        __syncthreads();
        {
            f16x8 av;
            if constexpr (MODE == 3) {
                const f16* A = (const f16*)Ap;
                av = *(const f16x8*)&A[(size_t)(mBase + sr) * 1024 + k0 + sq * 8];
            } else {
                const float* A = (const float*)Ap;
                const float4* p = (const float4*)&A[(size_t)(mBase + sr) * 1024 + k0 + sq * 8];
                float4 x0 = p[0], x1 = p[1];
                av[0] = (f16)x0.x; av[1] = (f16)x0.y; av[2] = (f16)x0.z; av[3] = (f16)x0.w;
                av[4] = (f16)x1.x; av[5] = (f16)x1.y; av[6] = (f16)x1.z; av[7] = (f16)x1.w;
            }
            *(f16x8*)&As[sr * 40 + sq * 8] = av;

            const float4* pw = (const float4*)&Wp[(size_t)(nBase + sr) * 1024 + k0 + sq * 8];
            float4 w0 = pw[0], w1 = pw[1];
            f16x8 bv;
            bv[0] = (f16)w0.x; bv[1] = (f16)w0.y; bv[2] = (f16)w0.z; bv[3] = (f16)w0.w;
            bv[4] = (f16)w1.x; bv[5] = (f16)w1.y; bv[6] = (f16)w1.z; bv[7] = (f16)w1.w;
            *(f16x8*)&Bs[sr * 40 + sq * 8] = bv;
        }
        __syncthreads();

        f16x8 af[2], bf[4];
#pragma unroll
        for (int mt = 0; mt < 2; mt++)
            af[mt] = *(const f16x8*)&As[(wm * 32 + mt * 16 + c) * 40 + g * 8];
#pragma unroll
        for (int nt = 0; nt < 4; nt++)
            bf[nt] = *(const f16x8*)&Bs[(wn * 64 + nt * 16 + c) * 40 + g * 8];
#pragma unroll
        for (int mt = 0; mt < 2; mt++)
#pragma unroll
            for (int nt = 0; nt < 4; nt++)
                acc[mt][nt] = __builtin_amdgcn_mfma_f32_16x16x32_f16(af[mt], bf[nt], acc[mt][nt], 0, 0, 0);
    }

#pragma unroll
    for (int mt = 0; mt < 2; mt++)
#pragma unroll
        for (int nt = 0; nt < 4; nt++) {
            int row0 = mBase + wm * 32 + mt * 16 + g * 4;
            int col = nBase + wn * 64 + nt * 16 + c;
            if constexpr (MODE == 3) {
#pragma unroll
                for (int r = 0; r < 4; r++)
                    ((float*)Cp)[(size_t)(row0 + r) * 1024 + col] = acc[mt][nt][r];
            } else if constexpr (MODE == 2) {
                int b = row0 >> 11, l0 = row0 & 2047;
                int h = col >> 6, dk = col & 63;
                f16x4 pv;
#pragma unroll
                for (int r = 0; r < 4; r++) pv[r] = (f16)acc[mt][nt][r];
                *(f16x4*)&((f16*)Cp)[((size_t)(b * 16 + h) * 64 + dk) * 2048 + l0] = pv;
            } else {
#pragma unroll
                for (int r = 0; r < 4; r++) {
                    int row = row0 + r;
                    float v = acc[mt][nt][r];
                    if constexpr (MODE == 0) v *= 0.0625f;
                    int b = row >> 11, l = row & 2047;
                    int h = col >> 6, dk = col & 63;
                    ((f16*)Cp)[((size_t)(b * 16 + h) * 2048 + l) * 64 + dk] = (f16)v;
                }
            }
        }
}

// ---------------------------------------------------------------------------
// Attention + exact 1.5-entmax; prefetched, packed-f16 scans.
// ---------------------------------------------------------------------------
__global__ __launch_bounds__(512, 4)
void attn_entmax(const f16* __restrict__ Q, const f16* __restrict__ Kh,
                 const f16* __restrict__ Vt, const u32* __restrict__ mbits,
                 f16* __restrict__ AO)
{
    constexpr int CAP = 512;
    // Overlay: bucket f16[16][512] (16 KB) dies at the taus barrier;
    // Ored f32 [8][16][68] (34.8 KB) lives after it.
    __shared__ __align__(16) char LB[8 * 16 * 68 * 4];
    __shared__ int cntS[16];
    __shared__ float redM[8][16];
    __shared__ float redN[2][8][16][2];
    __shared__ float tau3s[16], zmaxs[16], taus[16];

    f16 (*bucket)[CAP] = (f16 (*)[CAP])LB;
    float* Ored = (float*)LB;

    const int tid = threadIdx.x;
    const int w = tid >> 6, lane = tid & 63;
    const int g = lane >> 4, c = lane & 15;

    // XCD-aware swizzle: 4096 blocks = 8 XCD x (4 bh x 128 q-blocks)
    const int bid = blockIdx.x;
    const int q8 = bid >> 3;
    const int bh = (bid & 7) * 4 + (q8 >> 7);
    const int qb = (q8 & 127) * 16;
    const int b = bh >> 4, h = bh & 15;
    const int kbase = w * 256;

    if (tid < 16) cntS[tid] = 0;

    // ---- Q B-fragments (col = query = c, k-dim = d) ----
    const f16* qp = &Q[(size_t)(bh * 2048 + qb + c) * 64 + g * 8];
    f16x8 bq0 = *(const f16x8*)qp;
    f16x8 bq1 = *(const f16x8*)(qp + 32);

    const uint4* mp = (const uint4*)&mbits[(size_t)(b * 2048 + qb + c) * 64 + w * 8];
    uint4 mA = mp[0], mB = mp[1];
    u32 mb[8] = {mA.x, mA.y, mA.z, mA.w, mB.x, mB.y, mB.z, mB.w};

    // ---- scores: swapped QK^T, 2-tile chunks, double-buffered prefetch ----
    const f16* kp0 = &Kh[(size_t)(bh * 2048 + kbase + c) * 64 + g * 8];
    const f32x4 vz = {0.f, 0.f, 0.f, 0.f};

    f16x2 hS[32];
    f16x2 rmax; rmax.x = (f16)(-30000.f); rmax.y = (f16)(-30000.f);

    f16x8 kb[2][4];
#pragma unroll
    for (int i = 0; i < 2; i++) {
        const f16* kp = kp0 + (size_t)i * 1024;
        kb[0][2 * i]     = *(const f16x8*)kp;
        kb[0][2 * i + 1] = *(const f16x8*)(kp + 32);
    }
#pragma unroll
    for (int ch = 0; ch < 8; ch++) {
        if (ch < 7) {
#pragma unroll
            for (int i = 0; i < 2; i++) {
                const f16* kp = kp0 + (size_t)((ch + 1) * 2 + i) * 1024;
                kb[(ch + 1) & 1][2 * i]     = *(const f16x8*)kp;
                kb[(ch + 1) & 1][2 * i + 1] = *(const f16x8*)(kp + 32);
            }
        }
#pragma unroll
        for (int i = 0; i < 2; i++) {
            const int t = ch * 2 + i;
            f32x4 z = __builtin_amdgcn_mfma_f32_16x16x32_f16(kb[ch & 1][2 * i], bq0, vz, 0, 0, 0);
            z = __builtin_amdgcn_mfma_f32_16x16x32_f16(kb[ch & 1][2 * i + 1], bq1, z, 0, 0, 0);
            u32 b4 = mb[t >> 1] >> ((t & 1) * 16 + g * 4);
#pragma unroll
            for (int r = 0; r < 4; r++)
                if (!((b4 >> r) & 1)) z[r] = -30000.f;
            f16x2 p0, p1;
            p0.x = (f16)z[0]; p0.y = (f16)z[1];
            p1.x = (f16)z[2]; p1.y = (f16)z[3];
            hS[2 * t] = p0; hS[2 * t + 1] = p1;
            rmax = max2(rmax, max2(p0, p1));
        }
    }

    // ---- issue V chunk 0 early (latency hides under the solve phases) ----
    f16x4 vb[2][8];
    const size_t vrow = (size_t)(bh * 64 + c) * 2048 + kbase + g * 4;
#pragma unroll
    for (int i = 0; i < 2; i++)
#pragma unroll
        for (int nd = 0; nd < 4; nd++)
            vb[0][4 * i + nd] = *(const f16x4*)&Vt[vrow + (size_t)nd * 32768 + i * 16];

    // ---- zmax per query ----
    float zx = fmaxf((float)rmax.x, (float)rmax.y);
    zx = fmaxf(zx, __shfl_xor(zx, 16));
    zx = fmaxf(zx, __shfl_xor(zx, 32));
    if (lane < 16) redM[w][c] = zx;
    __syncthreads();
    float zmax = -3e38f;
#pragma unroll
    for (int ww = 0; ww < 8; ww++) zmax = fmaxf(zmax, redM[ww][c]);

    // ---- 2 cross-wave Newton iters from below (PACKED f16 scans) ----
    f16x2 zero2; zero2.x = (f16)0.f; zero2.y = (f16)0.f;
    float tau = zmax - 1.0f;
    int buf = 0;
#pragma unroll 1
    for (int it = 0; it < 2; ++it) {
        f16 tn = (f16)tau;
        f16x2 tv; tv.x = tn; tv.y = tn;
        f16x2 s1p = zero2, s2p = zero2;
#pragma unroll
        for (int i = 0; i < 32; i++) {
            f16x2 d = max2(hS[i] - tv, zero2);
            s1p = s1p + d;
            s2p = s2p + d * d;
        }
        float s1 = (float)s1p.x + (float)s1p.y;
        float s2 = (float)s2p.x + (float)s2p.y;
        s1 += __shfl_xor(s1, 16); s1 += __shfl_xor(s1, 32);
        s2 += __shfl_xor(s2, 16); s2 += __shfl_xor(s2, 32);
        if (lane < 16) { redN[buf][w][c][0] = s1; redN[buf][w][c][1] = s2; }
        __syncthreads();
        float a = 0.f, f = 0.f;
#pragma unroll
        for (int ww = 0; ww < 8; ww++) {
            float2 v2 = *(const float2*)&redN[buf][ww][c][0];
            a += v2.x; f += v2.y;
        }
        if (a > 1e-9f)
            tau = fminf(tau + (f - 1.0f) / (2.0f * a), zmax - 1e-3f);
        buf ^= 1;
    }
    if (w == 0 && lane < 16) { tau3s[c] = tau; zmaxs[c] = zmax; }

    // ---- filter survivors (0.01 margin covers packed-f16 Newton noise) ----
    const f16 thrh = (f16)(tau - 0.01f);
#pragma unroll
    for (int i = 0; i < 32; i++) {
        if (hS[i].x > thrh) { int id = atomicAdd(&cntS[c], 1); if (id < CAP) bucket[c][id] = hS[i].x; }
        if (hS[i].y > thrh) { int id = atomicAdd(&cntS[c], 1); if (id < CAP) bucket[c][id] = hS[i].y; }
    }
    __syncthreads();

    // ---- bucket solve: quarter-wave per query (4 queries / wave), f32 ----
    {
        const int qi = 4 * w + (lane >> 4);
        const int sl = lane & 15;
        const int cnt = min(cntS[qi], CAP);
        const int ns = (cnt + 15) >> 4;
        float tq = tau3s[qi];
        const float zq = zmaxs[qi];
#pragma unroll 1
        for (int it = 0; it < 4; ++it) {
            float s1 = 0.f, s2 = 0.f;
#pragma unroll 1
            for (int s = 0; s < ns; s++) {
                int i = sl + 16 * s;
                float v = (i < cnt) ? (float)bucket[qi][i] : -1e30f;
                float d = fmaxf(v - tq, 0.f);
                s1 += d; s2 = fmaf(d, d, s2);
            }
#pragma unroll
            for (int off = 1; off <= 8; off <<= 1) {
                s1 += __shfl_xor(s1, off);
                s2 += __shfl_xor(s2, off);
            }
            if (s1 > 1e-12f) tq = fminf(tq + (s2 - 1.0f) / (2.0f * s1), zq - 1e-3f);
        }
#pragma unroll 1
        for (int rf = 0; rf < 3; ++rf) {
            float kc = 0.f, s1 = 0.f, s2 = 0.f;
#pragma unroll 1
            for (int s = 0; s < ns; s++) {
                int i = sl + 16 * s;
                float v = (i < cnt) ? (float)bucket[qi][i] : -1e30f;
                float d = v - tq;
                if (d > 0.f) { kc += 1.f; s1 += d; s2 = fmaf(d, d, s2); }
            }
#pragma unroll
            for (int off = 1; off <= 8; off <<= 1) {
                kc += __shfl_xor(kc, off);
                s1 += __shfl_xor(s1, off);
                s2 += __shfl_xor(s2, off);
            }
            float K_ = fmaxf(kc, 1.0f);
            float disc = fmaxf(s1 * s1 - K_ * (s2 - 1.0f), 0.f);
            tq += (s1 - sqrtf(disc)) / K_;
        }
        if (sl == 0) taus[qi] = tq;
    }
    __syncthreads();     // taus ready; bucket dead -> LB becomes Ored

    // ---- P (packed) + PV with double-buffered V prefetch ----
    const f16 tch = (f16)taus[c];
    f16x2 tv2; tv2.x = tch; tv2.y = tch;
    f32x4 O[4];
#pragma unroll
    for (int nd = 0; nd < 4; nd++) O[nd] = vz;
#pragma unroll
    for (int ch = 0; ch < 8; ch++) {
        if (ch < 7) {
#pragma unroll
            for (int i = 0; i < 2; i++)
#pragma unroll
                for (int nd = 0; nd < 4; nd++)
                    vb[(ch + 1) & 1][4 * i + nd] =
                        *(const f16x4*)&Vt[vrow + (size_t)nd * 32768 + ((ch + 1) * 2 + i) * 16];
        }
#pragma unroll
        for (int i = 0; i < 2; i++) {
            const int t = ch * 2 + i;
            f16x2 da = max2(hS[2 * t] - tv2, zero2);
            f16x2 db = max2(hS[2 * t + 1] - tv2, zero2);
            da = da * da; db = db * db;
            union { f16x4 v4; f16x2 h2[2]; } pu;
            pu.h2[0] = da; pu.h2[1] = db;
#pragma unroll
            for (int nd = 0; nd < 4; nd++)
                O[nd] = __builtin_amdgcn_mfma_f32_16x16x16f16(vb[ch & 1][4 * i + nd], pu.v4, O[nd], 0, 0, 0);
        }
    }

    // ---- cross-wave O reduction (Ored overlays bucket) ----
#pragma unroll
    for (int nd = 0; nd < 4; nd++)
        *(f32x4*)&Ored[(w * 16 + c) * 68 + nd * 16 + g * 4] = O[nd];
    __syncthreads();

    const int qrow = tid >> 5;
    const int dp = tid & 31;
    float o0 = 0.f, o1 = 0.f;
#pragma unroll
    for (int ww = 0; ww < 8; ww++) {
        float2 v = *(const float2*)&Ored[(ww * 16 + qrow) * 68 + dp * 2];
        o0 += v.x; o1 += v.y;
    }
    f16x2 pk;
    pk.x = (f16)o0;
    pk.y = (f16)o1;
    *(f16x2*)&AO[(size_t)(b * 2048 + qb + qrow) * 1024 + h * 64 + dp * 2] = pk;
}

// ---------------------------------------------------------------------------
extern "C" void kernel_launch(void* const* d_in, const int* in_sizes, int n_in,
                              void* d_out, int out_size, void* d_ws, size_t ws_size,
                              hipStream_t stream)
{
    const float* q  = (const float*)d_in[0];
    const float* k  = (const float*)d_in[1];
    const float* v  = (const float*)d_in[2];
    const int* mask = (const int*)d_in[3];
    const float* wq = (const float*)d_in[4];
    const float* wk = (const float*)d_in[5];
    const float* wv = (const float*)d_in[6];
    const float* wo = (const float*)d_in[7];

    char* ws = (char*)d_ws;
    const size_t SZ = 8388608ull;            // 8 MB per f16 buffer
    f16* Qb  = (f16*)(ws);
    f16* Kb  = (f16*)(ws + SZ);
    f16* Vtb = (f16*)(ws + 2 * SZ);
    f16* AOb = (f16*)(ws + 3 * SZ);
    u32* Mb  = (u32*)(ws + 4 * SZ);          // 1 MB packed mask

    pack_mask<<<1024, 256, 0, stream>>>(mask, Mb);

    dim3 gg(32, 8);
    gemm_proj<0><<<gg, 512, 0, stream>>>(q, wq, Qb);
    gemm_proj<1><<<gg, 512, 0, stream>>>(k, wk, Kb);
    gemm_proj<2><<<gg, 512, 0, stream>>>(v, wv, Vtb);
    attn_entmax<<<4096, 512, 0, stream>>>(Qb, Kb, Vtb, Mb, AOb);
    gemm_proj<3><<<gg, 512, 0, stream>>>(AOb, wo, d_out);
}

// Round 9
// 435.963 us; speedup vs baseline: 1.8194x; 1.5461x over previous
//
#include <hip/hip_runtime.h>

// Shapes: B=2, L=2048, D_MODEL=1024, H=16, D_K=64
// Pipeline (R9: fragment-packed operand layouts -> fully coalesced attn loads):
//  0) pack_mask: mask int32 [B][L][L] -> Mp[b][qt][w][c][8] u32 (wave-contiguous).
//  1) gemm_proj<0/1>: Q/K proj; epilogue writes FRAGMENT-PACKED
//     Qp/Kp[bh][tile][half][c][g][8 f16]  (1 KB contiguous per wave-load).
//  2) gemm_proj<2>: V proj; epilogue writes Vp[bh][tile][nd][c][g][4 f16].
//  3) attn_entmax (= R6 algorithm, coalesced loads): 16 q x 2048 k, 8 waves,
//     XCD-swizzled grid. Swapped QK^T -> f16x2 scores in regs; 3 cross-wave
//     Newton iters from tau0=zmax-1 (monotone from below), filter survivors
//     z > tau3-1e-3 into per-query f32 buckets (CAP=512, stride 513),
//     quarter-wave solve (4 Newton + 3 exact support refines), PV from regs.
//  4) gemm_proj<3>: out = AO @ Wo^T -> f32 d_out.

typedef _Float16 f16;
typedef __attribute__((ext_vector_type(8))) _Float16 f16x8;
typedef __attribute__((ext_vector_type(4))) _Float16 f16x4;
typedef __attribute__((ext_vector_type(2))) _Float16 f16x2;
typedef __attribute__((ext_vector_type(4))) float f32x4;
typedef unsigned int u32;

static __device__ __forceinline__ f16x2 max2(f16x2 a, f16x2 b) {
    f16x2 r;
    r.x = a.x > b.x ? a.x : b.x;
    r.y = a.y > b.y ? a.y : b.y;
    return r;
}

// ---------------------------------------------------------------------------
// mask [2][2048][2048] int -> Mp[b][qt=128][w=8][c=16][8] u32
// ---------------------------------------------------------------------------
__global__ __launch_bounds__(256)
void pack_mask(const int* __restrict__ mask, u32* __restrict__ bits)
{
    int idx = blockIdx.x * 256 + threadIdx.x;        // (b*2048+q)*64 + wd
    const int4* p = (const int4*)&mask[(size_t)idx * 32];
    u32 v = 0;
#pragma unroll
    for (int i = 0; i < 8; i++) {
        int4 m = p[i];
        if (m.x != 0) v |= 1u << (i * 4 + 0);
        if (m.y != 0) v |= 1u << (i * 4 + 1);
        if (m.z != 0) v |= 1u << (i * 4 + 2);
        if (m.w != 0) v |= 1u << (i * 4 + 3);
    }
    const int wd = idx & 63;
    const int q = (idx >> 6) & 2047;
    const int b = idx >> 17;
    bits[(((size_t)(b * 128 + (q >> 4)) * 8 + (wd >> 3)) << 7) + ((q & 15) << 3) + (wd & 7)] = v;
}

// ---------------------------------------------------------------------------
// GEMM: C[M=4096, N=1024] = A[M,1024] * W[N,K=1024]^T
// MODE 0: Qp packed (*1/16)   1: Kp packed   2: Vp packed   3: OUT f32
// ---------------------------------------------------------------------------
template <int MODE>
__global__ __launch_bounds__(512)
void gemm_proj(const void* __restrict__ Ap, const float* __restrict__ Wp,
               void* __restrict__ Cp)
{
    __shared__ __align__(16) f16 As[128 * 40];
    __shared__ __align__(16) f16 Bs[128 * 40];

    const int tid = threadIdx.x;
    const int mBase = blockIdx.x * 128;
    const int nBase = blockIdx.y * 128;

    const int lane = tid & 63, w = tid >> 6;
    const int g = lane >> 4, c = lane & 15;
    const int wm = w >> 1, wn = w & 1;

    const int sr = tid >> 2;
    const int sq = tid & 3;

    f32x4 acc[2][4];
    const f32x4 vzero = {0.f, 0.f, 0.f, 0.f};
#pragma unroll
    for (int i = 0; i < 2; i++)
#pragma unroll
        for (int j = 0; j < 4; j++) acc[i][j] = vzero;

    for (int k0 = 0; k0 < 1024; k0 += 32) {
        __syncthreads();
        {
            f16x8 av;
            if constexpr (MODE == 3) {
                const f16* A = (const f16*)Ap;
                av = *(const f16x8*)&A[(size_t)(mBase + sr) * 1024 + k0 + sq * 8];
            } else {
                const float* A = (const float*)Ap;
                const float4* p = (const float4*)&A[(size_t)(mBase + sr) * 1024 + k0 + sq * 8];
                float4 x0 = p[0], x1 = p[1];
                av[0] = (f16)x0.x; av[1] = (f16)x0.y; av[2] = (f16)x0.z; av[3] = (f16)x0.w;
                av[4] = (f16)x1.x; av[5] = (f16)x1.y; av[6] = (f16)x1.z; av[7] = (f16)x1.w;
            }
            *(f16x8*)&As[sr * 40 + sq * 8] = av;

            const float4* pw = (const float4*)&Wp[(size_t)(nBase + sr) * 1024 + k0 + sq * 8];
            float4 w0 = pw[0], w1 = pw[1];
            f16x8 bv;
            bv[0] = (f16)w0.x; bv[1] = (f16)w0.y; bv[2] = (f16)w0.z; bv[3] = (f16)w0.w;
            bv[4] = (f16)w1.x; bv[5] = (f16)w1.y; bv[6] = (f16)w1.z; bv[7] = (f16)w1.w;
            *(f16x8*)&Bs[sr * 40 + sq * 8] = bv;
        }
        __syncthreads();

        f16x8 af[2], bf[4];
#pragma unroll
        for (int mt = 0; mt < 2; mt++)
            af[mt] = *(const f16x8*)&As[(wm * 32 + mt * 16 + c) * 40 + g * 8];
#pragma unroll
        for (int nt = 0; nt < 4; nt++)
            bf[nt] = *(const f16x8*)&Bs[(wn * 64 + nt * 16 + c) * 40 + g * 8];
#pragma unroll
        for (int mt = 0; mt < 2; mt++)
#pragma unroll
            for (int nt = 0; nt < 4; nt++)
                acc[mt][nt] = __builtin_amdgcn_mfma_f32_16x16x32_f16(af[mt], bf[nt], acc[mt][nt], 0, 0, 0);
    }

#pragma unroll
    for (int mt = 0; mt < 2; mt++)
#pragma unroll
        for (int nt = 0; nt < 4; nt++) {
            int row0 = mBase + wm * 32 + mt * 16 + g * 4;
            int col = nBase + wn * 64 + nt * 16 + c;
            if constexpr (MODE == 3) {
#pragma unroll
                for (int r = 0; r < 4; r++)
                    ((float*)Cp)[(size_t)(row0 + r) * 1024 + col] = acc[mt][nt][r];
            } else if constexpr (MODE == 2) {
                // Vp[bh][t][nd][c16][gv][4]: lane(c,g) holds V^T[d=nd*16+c][keys t*16+g*4..+4]
                int b = row0 >> 11, l0 = row0 & 2047;
                int h = col >> 6, dk = col & 63;
                int bh = b * 16 + h;
                int t = l0 >> 4, gv = (l0 & 15) >> 2;
                int nd = dk >> 4, c16 = dk & 15;
                f16x4 pv;
#pragma unroll
                for (int r = 0; r < 4; r++) pv[r] = (f16)acc[mt][nt][r];
                *(f16x4*)&((f16*)Cp)[(size_t)(bh * 128 + t) * 1024 + nd * 256 + c16 * 16 + gv * 4] = pv;
            } else {
                // Qp/Kp[bh][t][half][ck][gk][8]
#pragma unroll
                for (int r = 0; r < 4; r++) {
                    int row = row0 + r;
                    float v = acc[mt][nt][r];
                    if constexpr (MODE == 0) v *= 0.0625f;     // 1/sqrt(64) * 1/2
                    int b = row >> 11, l = row & 2047;
                    int h = col >> 6, dk = col & 63;
                    int bh = b * 16 + h;
                    int t = l >> 4, ck = l & 15;
                    int half = dk >> 5, gk = (dk >> 3) & 3, e = dk & 7;
                    ((f16*)Cp)[((size_t)(bh * 128 + t) * 2 + half) * 512 + ck * 32 + gk * 8 + e] = (f16)v;
                }
            }
        }
}

// ---------------------------------------------------------------------------
// Attention + exact 1.5-entmax (R6 algorithm, coalesced packed loads).
// ---------------------------------------------------------------------------
__global__ __launch_bounds__(512, 4)
void attn_entmax(const f16* __restrict__ Qp, const f16* __restrict__ Kp,
                 const f16* __restrict__ Vp, const u32* __restrict__ Mp,
                 f16* __restrict__ AO)
{
    constexpr int CAP = 512;
    constexpr int BSTR = 513;                        // padded row stride (f32)
    // Overlay: bucket f32[16][513] (32.8 KB) dies at taus barrier; Ored f32[8][16][68] after.
    __shared__ __align__(16) char LB[8 * 16 * 68 * 4];
    __shared__ int cntS[16];
    __shared__ float redM[8][16];
    __shared__ float redN[2][8][16][2];
    __shared__ float tau3s[16], zmaxs[16], taus[16];

    float* bucket = (float*)LB;
    float* Ored = (float*)LB;

    const int tid = threadIdx.x;
    const int w = tid >> 6, lane = tid & 63;
    const int g = lane >> 4, c = lane & 15;

    // XCD-aware swizzle: 4096 blocks = 8 XCD x (4 bh x 128 q-blocks)
    const int bid = blockIdx.x;
    const int q8 = bid >> 3;
    const int bh = (bid & 7) * 4 + (q8 >> 7);
    const int qt = q8 & 127;
    const int qb = qt * 16;
    const int b = bh >> 4, h = bh & 15;

    if (tid < 16) cntS[tid] = 0;

    // ---- Q B-fragments (coalesced: 1 KB per wave-instr) ----
    const f16* qbase = &Qp[(size_t)(bh * 128 + qt) * 1024 + c * 32 + g * 8];
    f16x8 bq0 = *(const f16x8*)qbase;
    f16x8 bq1 = *(const f16x8*)(qbase + 512);

    // ---- mask (coalesced: 512 B per wave-instr) ----
    const u32* mbase = &Mp[(((size_t)(b * 128 + qt) * 8 + w) << 7) + (c << 3)];
    uint4 mA = *(const uint4*)mbase;
    uint4 mB = *(const uint4*)(mbase + 4);
    u32 mb[8] = {mA.x, mA.y, mA.z, mA.w, mB.x, mB.y, mB.z, mB.w};

    // ---- scores S^T (swapped mfma(K,Q)); tiles T = w*16 + t ----
    f16x2 hS[32];
    const f32x4 vz = {0.f, 0.f, 0.f, 0.f};
    const f16* kbaseP = &Kp[(size_t)(bh * 128 + w * 16) * 1024 + c * 32 + g * 8];
#pragma unroll
    for (int t = 0; t < 16; t++) {
        const f16* kp = kbaseP + (size_t)t * 1024;
        f16x8 ka0 = *(const f16x8*)kp;
        f16x8 ka1 = *(const f16x8*)(kp + 512);
        f32x4 z = __builtin_amdgcn_mfma_f32_16x16x32_f16(ka0, bq0, vz, 0, 0, 0);
        z = __builtin_amdgcn_mfma_f32_16x16x32_f16(ka1, bq1, z, 0, 0, 0);
        u32 b4 = mb[t >> 1] >> ((t & 1) * 16 + g * 4);
#pragma unroll
        for (int r = 0; r < 4; r++)
            if (!((b4 >> r) & 1)) z[r] = -30000.f;
        f16x2 p0, p1;
        p0.x = (f16)z[0]; p0.y = (f16)z[1];
        p1.x = (f16)z[2]; p1.y = (f16)z[3];
        hS[2 * t] = p0;
        hS[2 * t + 1] = p1;
    }

    // ---- zmax per query ----
    f16x2 m2 = hS[0];
#pragma unroll
    for (int i = 1; i < 32; i++) m2 = max2(m2, hS[i]);
    float zx = fmaxf((float)m2.x, (float)m2.y);
    zx = fmaxf(zx, __shfl_xor(zx, 16));
    zx = fmaxf(zx, __shfl_xor(zx, 32));
    if (lane < 16) redM[w][c] = zx;
    __syncthreads();
    float zmax = -3e38f;
#pragma unroll
    for (int ww = 0; ww < 8; ww++) zmax = fmaxf(zmax, redM[ww][c]);

    // ---- 3 cross-wave Newton iters from below (f32 sums) -> tau3 <= tau* ----
    float tau = zmax - 1.0f;
    int buf = 0;
#pragma unroll 1
    for (int it = 0; it < 3; ++it) {
        float s1 = 0.f, s2 = 0.f;
#pragma unroll
        for (int i = 0; i < 32; i++) {
            float lo = fmaxf((float)hS[i].x - tau, 0.f);
            float hi = fmaxf((float)hS[i].y - tau, 0.f);
            s1 += lo + hi;
            s2 = fmaf(lo, lo, fmaf(hi, hi, s2));
        }
        s1 += __shfl_xor(s1, 16); s1 += __shfl_xor(s1, 32);
        s2 += __shfl_xor(s2, 16); s2 += __shfl_xor(s2, 32);
        if (lane < 16) { redN[buf][w][c][0] = s1; redN[buf][w][c][1] = s2; }
        __syncthreads();
        float a = 0.f, f = 0.f;
#pragma unroll
        for (int ww = 0; ww < 8; ww++) {
            float2 v2 = *(const float2*)&redN[buf][ww][c][0];
            a += v2.x; f += v2.y;
        }
        if (a > 1e-12f)
            tau = fminf(tau + (f - 1.0f) / (2.0f * a), zmax - 1e-3f);
        buf ^= 1;
    }
    if (w == 0 && lane < 16) { tau3s[c] = tau; zmaxs[c] = zmax; }

    // ---- filter survivors (z > tau3 - eps ⊇ true support) into f32 buckets ----
    const float thr = tau - 1e-3f;
#pragma unroll
    for (int i = 0; i < 32; i++) {
        float lo = (float)hS[i].x, hi = (float)hS[i].y;
        if (lo > thr) { int id = atomicAdd(&cntS[c], 1); if (id < CAP) bucket[c * BSTR + id] = lo; }
        if (hi > thr) { int id = atomicAdd(&cntS[c], 1); if (id < CAP) bucket[c * BSTR + id] = hi; }
    }
    __syncthreads();

    // ---- bucket solve: quarter-wave per query (4 queries / wave), f32 ----
    {
        const int qi = 4 * w + (lane >> 4);
        const int sl = lane & 15;
        const int cnt = min(cntS[qi], CAP);
        const int ns = (cnt + 15) >> 4;
        float tq = tau3s[qi];
        const float zq = zmaxs[qi];
#pragma unroll 1
        for (int it = 0; it < 4; ++it) {
            float s1 = 0.f, s2 = 0.f;
#pragma unroll 1
            for (int s = 0; s < ns; s++) {
                int i = sl + 16 * s;
                float v = (i < cnt) ? bucket[qi * BSTR + i] : -1e30f;
                float d = fmaxf(v - tq, 0.f);
                s1 += d; s2 = fmaf(d, d, s2);
            }
#pragma unroll
            for (int off = 1; off <= 8; off <<= 1) {
                s1 += __shfl_xor(s1, off);
                s2 += __shfl_xor(s2, off);
            }
            if (s1 > 1e-12f) tq = fminf(tq + (s2 - 1.0f) / (2.0f * s1), zq - 1e-3f);
        }
#pragma unroll 1
        for (int rf = 0; rf < 3; ++rf) {
            float kc = 0.f, s1 = 0.f, s2 = 0.f;
#pragma unroll 1
            for (int s = 0; s < ns; s++) {
                int i = sl + 16 * s;
                float v = (i < cnt) ? bucket[qi * BSTR + i] : -1e30f;
                float d = v - tq;
                if (d > 0.f) { kc += 1.f; s1 += d; s2 = fmaf(d, d, s2); }
            }
#pragma unroll
            for (int off = 1; off <= 8; off <<= 1) {
                kc += __shfl_xor(kc, off);
                s1 += __shfl_xor(s1, off);
                s2 += __shfl_xor(s2, off);
            }
            float K_ = fmaxf(kc, 1.0f);
            float disc = fmaxf(s1 * s1 - K_ * (s2 - 1.0f), 0.f);
            tq += (s1 - sqrtf(disc)) / K_;
        }
        if (sl == 0) taus[qi] = tq;
    }
    __syncthreads();     // taus ready; bucket dead -> LB becomes Ored

    // ---- P = ((z-tau)_+)^2 -> PV from regs; Vp loads coalesced (512 B/instr) ----
    const float tc = taus[c];
    f32x4 O[4];
#pragma unroll
    for (int nd = 0; nd < 4; nd++) O[nd] = vz;
    const f16* vbase = &Vp[(size_t)(bh * 128 + w * 16) * 1024 + c * 16 + g * 4];
#pragma unroll
    for (int t = 0; t < 16; t++) {
        f16x4 pf;
        float d0 = fmaxf((float)hS[2 * t].x - tc, 0.f);
        float d1 = fmaxf((float)hS[2 * t].y - tc, 0.f);
        float d2 = fmaxf((float)hS[2 * t + 1].x - tc, 0.f);
        float d3 = fmaxf((float)hS[2 * t + 1].y - tc, 0.f);
        pf[0] = (f16)(d0 * d0);
        pf[1] = (f16)(d1 * d1);
        pf[2] = (f16)(d2 * d2);
        pf[3] = (f16)(d3 * d3);
        const f16* vp = vbase + (size_t)t * 1024;
#pragma unroll
        for (int nd = 0; nd < 4; nd++) {
            f16x4 va = *(const f16x4*)(vp + nd * 256);
            O[nd] = __builtin_amdgcn_mfma_f32_16x16x16f16(va, pf, O[nd], 0, 0, 0);
        }
    }

    // ---- cross-wave O reduction (Ored overlays bucket) ----
#pragma unroll
    for (int nd = 0; nd < 4; nd++)
        *(f32x4*)&Ored[(w * 16 + c) * 68 + nd * 16 + g * 4] = O[nd];
    __syncthreads();

    const int qrow = tid >> 5;
    const int dp = tid & 31;
    float o0 = 0.f, o1 = 0.f;
#pragma unroll
    for (int ww = 0; ww < 8; ww++) {
        float2 v = *(const float2*)&Ored[(ww * 16 + qrow) * 68 + dp * 2];
        o0 += v.x; o1 += v.y;
    }
    f16x2 pk;
    pk.x = (f16)o0;
    pk.y = (f16)o1;
    *(f16x2*)&AO[(size_t)(b * 2048 + qb + qrow) * 1024 + h * 64 + dp * 2] = pk;
}

// ---------------------------------------------------------------------------
extern "C" void kernel_launch(void* const* d_in, const int* in_sizes, int n_in,
                              void* d_out, int out_size, void* d_ws, size_t ws_size,
                              hipStream_t stream)
{
    const float* q  = (const float*)d_in[0];
    const float* k  = (const float*)d_in[1];
    const float* v  = (const float*)d_in[2];
    const int* mask = (const int*)d_in[3];
    const float* wq = (const float*)d_in[4];
    const float* wk = (const float*)d_in[5];
    const float* wv = (const float*)d_in[6];
    const float* wo = (const float*)d_in[7];

    char* ws = (char*)d_ws;
    const size_t SZ = 8388608ull;            // 8 MB per f16 buffer
    f16* Qb  = (f16*)(ws);
    f16* Kb  = (f16*)(ws + SZ);
    f16* Vb  = (f16*)(ws + 2 * SZ);
    f16* AOb = (f16*)(ws + 3 * SZ);
    u32* Mb  = (u32*)(ws + 4 * SZ);          // 1 MB packed mask

    pack_mask<<<1024, 256, 0, stream>>>(mask, Mb);

    dim3 gg(32, 8);
    gemm_proj<0><<<gg, 512, 0, stream>>>(q, wq, Qb);
    gemm_proj<1><<<gg, 512, 0, stream>>>(k, wk, Kb);
    gemm_proj<2><<<gg, 512, 0, stream>>>(v, wv, Vb);
    attn_entmax<<<4096, 512, 0, stream>>>(Qb, Kb, Vb, Mb, AOb);
    gemm_proj<3><<<gg, 512, 0, stream>>>(AOb, wo, d_out);
}

// Round 11
// 427.056 us; speedup vs baseline: 1.8574x; 1.0209x over previous
//
#include <hip/hip_runtime.h>

// Shapes: B=2, L=2048, D_MODEL=1024, H=16, D_K=64
// Pipeline (R11 = R10 with cvt_pkrtz type fix):
//  0) pack_mask: mask int32 [B][L][L] -> Mp[b][qt][w][c][8] u32 (wave-contiguous).
//  1) gemm_proj<0/1>: Q/K proj; epilogue writes FRAGMENT-PACKED
//     Qp/Kp[bh][tile][half][c][g][8 f16]  (1 KB contiguous per wave-load).
//  2) gemm_proj<2>: V proj; epilogue writes Vp[bh][tile][nd][c][g][4 f16].
//  3) attn_entmax: 16 q x 2048 k, 8 waves, XCD-swizzled grid, coalesced loads.
//     Swapped QK^T -> f16x2 scores (cvt_pkrtz pack + fused pk_max tracking);
//     3 cross-wave Newton iters with PACKED f16 scans (pk ops + packed shuffle
//     reduce, f32 cross-wave only), filter at tau3-0.02 via f16 compares into
//     f32 buckets (CAP=512, stride 513), quarter-wave f32 solve (4 Newton +
//     3 exact support refines), P in packed f16 -> PV from regs (16x16x16).
//  4) gemm_proj<3>: out = AO @ Wo^T -> f32 d_out.

typedef _Float16 f16;
typedef __attribute__((ext_vector_type(8))) _Float16 f16x8;
typedef __attribute__((ext_vector_type(4))) _Float16 f16x4;
typedef __attribute__((ext_vector_type(2))) _Float16 f16x2;
typedef __attribute__((ext_vector_type(4))) float f32x4;
typedef unsigned int u32;

static __device__ __forceinline__ f16x2 max2(f16x2 a, f16x2 b) {
    f16x2 r;
    r.x = a.x > b.x ? a.x : b.x;
    r.y = a.y > b.y ? a.y : b.y;
    return r;
}

static __device__ __forceinline__ f16x2 shfl2(f16x2 v, int off) {
    union { f16x2 h; int i; } u;
    u.h = v;
    u.i = __shfl_xor(u.i, off);
    return u.h;
}

static __device__ __forceinline__ f16x2 pkrtz(float a, float b) {
    union { __fp16 __attribute__((ext_vector_type(2))) p; f16x2 h; } u;
    u.p = __builtin_amdgcn_cvt_pkrtz(a, b);
    return u.h;
}

// ---------------------------------------------------------------------------
// mask [2][2048][2048] int -> Mp[b][qt=128][w=8][c=16][8] u32
// ---------------------------------------------------------------------------
__global__ __launch_bounds__(256)
void pack_mask(const int* __restrict__ mask, u32* __restrict__ bits)
{
    int idx = blockIdx.x * 256 + threadIdx.x;        // (b*2048+q)*64 + wd
    const int4* p = (const int4*)&mask[(size_t)idx * 32];
    u32 v = 0;
#pragma unroll
    for (int i = 0; i < 8; i++) {
        int4 m = p[i];
        if (m.x != 0) v |= 1u << (i * 4 + 0);
        if (m.y != 0) v |= 1u << (i * 4 + 1);
        if (m.z != 0) v |= 1u << (i * 4 + 2);
        if (m.w != 0) v |= 1u << (i * 4 + 3);
    }
    const int wd = idx & 63;
    const int q = (idx >> 6) & 2047;
    const int b = idx >> 17;
    bits[(((size_t)(b * 128 + (q >> 4)) * 8 + (wd >> 3)) << 7) + ((q & 15) << 3) + (wd & 7)] = v;
}

// ---------------------------------------------------------------------------
// GEMM: C[M=4096, N=1024] = A[M,1024] * W[N,K=1024]^T
// MODE 0: Qp packed (*1/16)   1: Kp packed   2: Vp packed   3: OUT f32
// ---------------------------------------------------------------------------
template <int MODE>
__global__ __launch_bounds__(512)
void gemm_proj(const void* __restrict__ Ap, const float* __restrict__ Wp,
               void* __restrict__ Cp)
{
    __shared__ __align__(16) f16 As[128 * 40];
    __shared__ __align__(16) f16 Bs[128 * 40];

    const int tid = threadIdx.x;
    const int mBase = blockIdx.x * 128;
    const int nBase = blockIdx.y * 128;

    const int lane = tid & 63, w = tid >> 6;
    const int g = lane >> 4, c = lane & 15;
    const int wm = w >> 1, wn = w & 1;

    const int sr = tid >> 2;
    const int sq = tid & 3;

    f32x4 acc[2][4];
    const f32x4 vzero = {0.f, 0.f, 0.f, 0.f};
#pragma unroll
    for (int i = 0; i < 2; i++)
#pragma unroll
        for (int j = 0; j < 4; j++) acc[i][j] = vzero;

    for (int k0 = 0; k0 < 1024; k0 += 32) {
        __syncthreads();
        {
            f16x8 av;
            if constexpr (MODE == 3) {
                const f16* A = (const f16*)Ap;
                av = *(const f16x8*)&A[(size_t)(mBase + sr) * 1024 + k0 + sq * 8];
            } else {
                const float* A = (const float*)Ap;
                const float4* p = (const float4*)&A[(size_t)(mBase + sr) * 1024 + k0 + sq * 8];
                float4 x0 = p[0], x1 = p[1];
                av[0] = (f16)x0.x; av[1] = (f16)x0.y; av[2] = (f16)x0.z; av[3] = (f16)x0.w;
                av[4] = (f16)x1.x; av[5] = (f16)x1.y; av[6] = (f16)x1.z; av[7] = (f16)x1.w;
            }
            *(f16x8*)&As[sr * 40 + sq * 8] = av;

            const float4* pw = (const float4*)&Wp[(size_t)(nBase + sr) * 1024 + k0 + sq * 8];
            float4 w0 = pw[0], w1 = pw[1];
            f16x8 bv;
            bv[0] = (f16)w0.x; bv[1] = (f16)w0.y; bv[2] = (f16)w0.z; bv[3] = (f16)w0.w;
            bv[4] = (f16)w1.x; bv[5] = (f16)w1.y; bv[6] = (f16)w1.z; bv[7] = (f16)w1.w;
            *(f16x8*)&Bs[sr * 40 + sq * 8] = bv;
        }
        __syncthreads();

        f16x8 af[2], bf[4];
#pragma unroll
        for (int mt = 0; mt < 2; mt++)
            af[mt] = *(const f16x8*)&As[(wm * 32 + mt * 16 + c) * 40 + g * 8];
#pragma unroll
        for (int nt = 0; nt < 4; nt++)
            bf[nt] = *(const f16x8*)&Bs[(wn * 64 + nt * 16 + c) * 40 + g * 8];
#pragma unroll
        for (int mt = 0; mt < 2; mt++)
#pragma unroll
            for (int nt = 0; nt < 4; nt++)
                acc[mt][nt] = __builtin_amdgcn_mfma_f32_16x16x32_f16(af[mt], bf[nt], acc[mt][nt], 0, 0, 0);
    }

#pragma unroll
    for (int mt = 0; mt < 2; mt++)
#pragma unroll
        for (int nt = 0; nt < 4; nt++) {
            int row0 = mBase + wm * 32 + mt * 16 + g * 4;
            int col = nBase + wn * 64 + nt * 16 + c;
            if constexpr (MODE == 3) {
#pragma unroll
                for (int r = 0; r < 4; r++)
                    ((float*)Cp)[(size_t)(row0 + r) * 1024 + col] = acc[mt][nt][r];
            } else if constexpr (MODE == 2) {
                // Vp[bh][t][nd][c16][gv][4]: lane(c,g) holds V^T[d=nd*16+c][keys t*16+g*4..+4]
                int b = row0 >> 11, l0 = row0 & 2047;
                int h = col >> 6, dk = col & 63;
                int bh = b * 16 + h;
                int t = l0 >> 4, gv = (l0 & 15) >> 2;
                int nd = dk >> 4, c16 = dk & 15;
                f16x4 pv;
#pragma unroll
                for (int r = 0; r < 4; r++) pv[r] = (f16)acc[mt][nt][r];
                *(f16x4*)&((f16*)Cp)[(size_t)(bh * 128 + t) * 1024 + nd * 256 + c16 * 16 + gv * 4] = pv;
            } else {
                // Qp/Kp[bh][t][half][ck][gk][8]
#pragma unroll
                for (int r = 0; r < 4; r++) {
                    int row = row0 + r;
                    float v = acc[mt][nt][r];
                    if constexpr (MODE == 0) v *= 0.0625f;     // 1/sqrt(64) * 1/2
                    int b = row >> 11, l = row & 2047;
                    int h = col >> 6, dk = col & 63;
                    int bh = b * 16 + h;
                    int t = l >> 4, ck = l & 15;
                    int half = dk >> 5, gk = (dk >> 3) & 3, e = dk & 7;
                    ((f16*)Cp)[((size_t)(bh * 128 + t) * 2 + half) * 512 + ck * 32 + gk * 8 + e] = (f16)v;
                }
            }
        }
}

// ---------------------------------------------------------------------------
// Attention + exact 1.5-entmax (coalesced packed loads, packed-f16 VALU).
// ---------------------------------------------------------------------------
__global__ __launch_bounds__(512, 4)
void attn_entmax(const f16* __restrict__ Qp, const f16* __restrict__ Kp,
                 const f16* __restrict__ Vp, const u32* __restrict__ Mp,
                 f16* __restrict__ AO)
{
    constexpr int CAP = 512;
    constexpr int BSTR = 513;                        // padded row stride (f32)
    // Overlay: bucket f32[16][513] (32.8 KB) dies at taus barrier; Ored f32[8][16][68] after.
    __shared__ __align__(16) char LB[8 * 16 * 68 * 4];
    __shared__ int cntS[16];
    __shared__ float redM[8][16];
    __shared__ float redN[2][8][16][2];
    __shared__ float tau3s[16], zmaxs[16], taus[16];

    float* bucket = (float*)LB;
    float* Ored = (float*)LB;

    const int tid = threadIdx.x;
    const int w = tid >> 6, lane = tid & 63;
    const int g = lane >> 4, c = lane & 15;

    // XCD-aware swizzle: 4096 blocks = 8 XCD x (4 bh x 128 q-blocks)
    const int bid = blockIdx.x;
    const int q8 = bid >> 3;
    const int bh = (bid & 7) * 4 + (q8 >> 7);
    const int qt = q8 & 127;
    const int qb = qt * 16;
    const int b = bh >> 4, h = bh & 15;

    if (tid < 16) cntS[tid] = 0;

    // ---- Q B-fragments (coalesced: 1 KB per wave-instr) ----
    const f16* qbase = &Qp[(size_t)(bh * 128 + qt) * 1024 + c * 32 + g * 8];
    f16x8 bq0 = *(const f16x8*)qbase;
    f16x8 bq1 = *(const f16x8*)(qbase + 512);

    // ---- mask (coalesced: 512 B per wave-instr) ----
    const u32* mbase = &Mp[(((size_t)(b * 128 + qt) * 8 + w) << 7) + (c << 3)];
    uint4 mA = *(const uint4*)mbase;
    uint4 mB = *(const uint4*)(mbase + 4);
    u32 mb[8] = {mA.x, mA.y, mA.z, mA.w, mB.x, mB.y, mB.z, mB.w};

    // ---- scores S^T (swapped mfma(K,Q)) with fused pkrtz pack + max track ----
    f16x2 hS[32];
    f16x2 rmax; rmax.x = (f16)(-30000.f); rmax.y = (f16)(-30000.f);
    const f32x4 vz = {0.f, 0.f, 0.f, 0.f};
    const f16* kbaseP = &Kp[(size_t)(bh * 128 + w * 16) * 1024 + c * 32 + g * 8];
#pragma unroll
    for (int t = 0; t < 16; t++) {
        const f16* kp = kbaseP + (size_t)t * 1024;
        f16x8 ka0 = *(const f16x8*)kp;
        f16x8 ka1 = *(const f16x8*)(kp + 512);
        f32x4 z = __builtin_amdgcn_mfma_f32_16x16x32_f16(ka0, bq0, vz, 0, 0, 0);
        z = __builtin_amdgcn_mfma_f32_16x16x32_f16(ka1, bq1, z, 0, 0, 0);
        u32 b4 = mb[t >> 1] >> ((t & 1) * 16 + g * 4);
#pragma unroll
        for (int r = 0; r < 4; r++)
            if (!((b4 >> r) & 1)) z[r] = -30000.f;
        f16x2 p0 = pkrtz(z[0], z[1]);
        f16x2 p1 = pkrtz(z[2], z[3]);
        hS[2 * t] = p0;
        hS[2 * t + 1] = p1;
        rmax = max2(rmax, max2(p0, p1));
    }

    // ---- zmax per query ----
    float zx = fmaxf((float)rmax.x, (float)rmax.y);
    zx = fmaxf(zx, __shfl_xor(zx, 16));
    zx = fmaxf(zx, __shfl_xor(zx, 32));
    if (lane < 16) redM[w][c] = zx;
    __syncthreads();
    float zmax = -3e38f;
#pragma unroll
    for (int ww = 0; ww < 8; ww++) zmax = fmaxf(zmax, redM[ww][c]);

    // ---- 3 cross-wave Newton iters from below (PACKED f16 scans) ----
    f16x2 zero2; zero2.x = (f16)0.f; zero2.y = (f16)0.f;
    float tau = zmax - 1.0f;
    int buf = 0;
#pragma unroll 1
    for (int it = 0; it < 3; ++it) {
        f16 tn = (f16)tau;
        f16x2 tv; tv.x = tn; tv.y = tn;
        f16x2 s1p = zero2, s2p = zero2;
#pragma unroll
        for (int i = 0; i < 32; i++) {
            f16x2 d = max2(hS[i] - tv, zero2);
            s1p = s1p + d;
            s2p = s2p + d * d;
        }
        s1p = s1p + shfl2(s1p, 16);
        s2p = s2p + shfl2(s2p, 16);
        s1p = s1p + shfl2(s1p, 32);
        s2p = s2p + shfl2(s2p, 32);
        float s1 = (float)s1p.x + (float)s1p.y;
        float s2 = (float)s2p.x + (float)s2p.y;
        if (lane < 16) { redN[buf][w][c][0] = s1; redN[buf][w][c][1] = s2; }
        __syncthreads();
        float a = 0.f, f = 0.f;
#pragma unroll
        for (int ww = 0; ww < 8; ww++) {
            float2 v2 = *(const float2*)&redN[buf][ww][c][0];
            a += v2.x; f += v2.y;
        }
        if (a > 1e-9f)
            tau = fminf(tau + (f - 1.0f) / (2.0f * a), zmax - 1e-3f);
        buf ^= 1;
    }
    if (w == 0 && lane < 16) { tau3s[c] = tau; zmaxs[c] = zmax; }

    // ---- filter survivors (f16 compares, 0.02 margin for packed-Newton noise) ----
    const f16 thrh = (f16)(tau - 0.02f);
#pragma unroll
    for (int i = 0; i < 32; i++) {
        if (hS[i].x > thrh) { int id = atomicAdd(&cntS[c], 1); if (id < CAP) bucket[c * BSTR + id] = (float)hS[i].x; }
        if (hS[i].y > thrh) { int id = atomicAdd(&cntS[c], 1); if (id < CAP) bucket[c * BSTR + id] = (float)hS[i].y; }
    }
    __syncthreads();

    // ---- bucket solve: quarter-wave per query (4 queries / wave), f32 ----
    {
        const int qi = 4 * w + (lane >> 4);
        const int sl = lane & 15;
        const int cnt = min(cntS[qi], CAP);
        const int ns = (cnt + 15) >> 4;
        float tq = tau3s[qi];
        const float zq = zmaxs[qi];
#pragma unroll 1
        for (int it = 0; it < 4; ++it) {
            float s1 = 0.f, s2 = 0.f;
#pragma unroll 1
            for (int s = 0; s < ns; s++) {
                int i = sl + 16 * s;
                float v = (i < cnt) ? bucket[qi * BSTR + i] : -1e30f;
                float d = fmaxf(v - tq, 0.f);
                s1 += d; s2 = fmaf(d, d, s2);
            }
#pragma unroll
            for (int off = 1; off <= 8; off <<= 1) {
                s1 += __shfl_xor(s1, off);
                s2 += __shfl_xor(s2, off);
            }
            if (s1 > 1e-12f) tq = fminf(tq + (s2 - 1.0f) / (2.0f * s1), zq - 1e-3f);
        }
#pragma unroll 1
        for (int rf = 0; rf < 3; ++rf) {
            float kc = 0.f, s1 = 0.f, s2 = 0.f;
#pragma unroll 1
            for (int s = 0; s < ns; s++) {
                int i = sl + 16 * s;
                float v = (i < cnt) ? bucket[qi * BSTR + i] : -1e30f;
                float d = v - tq;
                if (d > 0.f) { kc += 1.f; s1 += d; s2 = fmaf(d, d, s2); }
            }
#pragma unroll
            for (int off = 1; off <= 8; off <<= 1) {
                kc += __shfl_xor(kc, off);
                s1 += __shfl_xor(s1, off);
                s2 += __shfl_xor(s2, off);
            }
            float K_ = fmaxf(kc, 1.0f);
            float disc = fmaxf(s1 * s1 - K_ * (s2 - 1.0f), 0.f);
            tq += (s1 - sqrtf(disc)) / K_;
        }
        if (sl == 0) taus[qi] = tq;
    }
    __syncthreads();     // taus ready; bucket dead -> LB becomes Ored

    // ---- P = ((z-tau)_+)^2 PACKED -> PV from regs (coalesced Vp loads) ----
    const f16 tch = (f16)taus[c];
    f16x2 tv2; tv2.x = tch; tv2.y = tch;
    f32x4 O[4];
#pragma unroll
    for (int nd = 0; nd < 4; nd++) O[nd] = vz;
    const f16* vbase = &Vp[(size_t)(bh * 128 + w * 16) * 1024 + c * 16 + g * 4];
#pragma unroll
    for (int t = 0; t < 16; t++) {
        f16x2 da = max2(hS[2 * t] - tv2, zero2);
        f16x2 db = max2(hS[2 * t + 1] - tv2, zero2);
        da = da * da;
        db = db * db;
        union { f16x4 v4; f16x2 h2[2]; } pu;
        pu.h2[0] = da; pu.h2[1] = db;
        const f16* vp = vbase + (size_t)t * 1024;
#pragma unroll
        for (int nd = 0; nd < 4; nd++) {
            f16x4 va = *(const f16x4*)(vp + nd * 256);
            O[nd] = __builtin_amdgcn_mfma_f32_16x16x16f16(va, pu.v4, O[nd], 0, 0, 0);
        }
    }

    // ---- cross-wave O reduction (Ored overlays bucket) ----
#pragma unroll
    for (int nd = 0; nd < 4; nd++)
        *(f32x4*)&Ored[(w * 16 + c) * 68 + nd * 16 + g * 4] = O[nd];
    __syncthreads();

    const int qrow = tid >> 5;
    const int dp = tid & 31;
    float o0 = 0.f, o1 = 0.f;
#pragma unroll
    for (int ww = 0; ww < 8; ww++) {
        float2 v = *(const float2*)&Ored[(ww * 16 + qrow) * 68 + dp * 2];
        o0 += v.x; o1 += v.y;
    }
    f16x2 pk = pkrtz(o0, o1);
    *(f16x2*)&AO[(size_t)(b * 2048 + qb + qrow) * 1024 + h * 64 + dp * 2] = pk;
}

// ---------------------------------------------------------------------------
extern "C" void kernel_launch(void* const* d_in, const int* in_sizes, int n_in,
                              void* d_out, int out_size, void* d_ws, size_t ws_size,
                              hipStream_t stream)
{
    const float* q  = (const float*)d_in[0];
    const float* k  = (const float*)d_in[1];
    const float* v  = (const float*)d_in[2];
    const int* mask = (const int*)d_in[3];
    const float* wq = (const float*)d_in[4];
    const float* wk = (const float*)d_in[5];
    const float* wv = (const float*)d_in[6];
    const float* wo = (const float*)d_in[7];

    char* ws = (char*)d_ws;
    const size_t SZ = 8388608ull;            // 8 MB per f16 buffer
    f16* Qb  = (f16*)(ws);
    f16* Kb  = (f16*)(ws + SZ);
    f16* Vb  = (f16*)(ws + 2 * SZ);
    f16* AOb = (f16*)(ws + 3 * SZ);
    u32* Mb  = (u32*)(ws + 4 * SZ);          // 1 MB packed mask

    pack_mask<<<1024, 256, 0, stream>>>(mask, Mb);

    dim3 gg(32, 8);
    gemm_proj<0><<<gg, 512, 0, stream>>>(q, wq, Qb);
    gemm_proj<1><<<gg, 512, 0, stream>>>(k, wk, Kb);
    gemm_proj<2><<<gg, 512, 0, stream>>>(v, wv, Vb);
    attn_entmax<<<4096, 512, 0, stream>>>(Qb, Kb, Vb, Mb, AOb);
    gemm_proj<3><<<gg, 512, 0, stream>>>(AOb, wo, d_out);
}